// Round 7
// baseline (261.788 us; speedup 1.0000x reference)
//
#include <hip/hip_runtime.h>
#include <hip/hip_bf16.h>
#include <math.h>

#define SEQ 4096
#define HID 1024
#define DH  64
#define NB  8
#define QSCALE 0.18033688011112042f   // 0.125 * log2(e): folds softmax scale + exp->exp2

typedef unsigned short ushort_t;
typedef unsigned int   uint_t;
typedef __attribute__((ext_vector_type(8)))  short  bf16x8;
typedef __attribute__((ext_vector_type(4)))  float  f32x4;
typedef __attribute__((ext_vector_type(16))) float  f32x16;
typedef __attribute__((ext_vector_type(4)))  uint_t u32x4;
typedef __attribute__((ext_vector_type(2)))  uint_t u32x2;

static __device__ __forceinline__ ushort_t f2bf(float f) {
    __hip_bfloat16 h = __float2bfloat16(f);   // RNE
    return *reinterpret_cast<ushort_t*>(&h);
}
// fast round-to-nearest bf16 (no NaN path; inputs finite)
static __device__ __forceinline__ ushort_t f2bf_fast(float f) {
    uint_t u = __float_as_uint(f);
    return (ushort_t)((u + 0x8000u) >> 16);
}
static __device__ __forceinline__ uint_t bfpair(float lo, float hi) {
    return (uint_t)f2bf_fast(lo) | ((uint_t)f2bf_fast(hi) << 16);
}

// async global->LDS DMA, 16 B per lane; lds dest = wave-uniform base + lane*16
static __device__ __forceinline__ void gld_lds16(const void* g, void* s) {
    __builtin_amdgcn_global_load_lds(
        (const __attribute__((address_space(1))) void*)g,
        (__attribute__((address_space(3))) void*)s, 16, 0, 0);
}

// ---------------------------------------------------------------------------
// Kernel 0: build wts = [Wq*QSCALE | Wk | Wv] transposed to [col][k], bf16,
// pre-swizzled per 64-k tile so proj can stage it as a flat DMA copy.
// ---------------------------------------------------------------------------
__global__ __launch_bounds__(256) void prep_w(
    const float* __restrict__ Wq, const float* __restrict__ Wk,
    const float* __restrict__ Wv, ushort_t* __restrict__ wts)
{
    __shared__ ushort_t tr[64][72];   // [k][c] bf16
    const int bx   = blockIdx.x;      // 48 = 3 mats x 16 k-tiles
    const int mmat = bx >> 4;
    const int kt   = bx & 15;
    const float* W  = (mmat == 0) ? Wq : (mmat == 1) ? Wk : Wv;
    const float  sc = (mmat == 0) ? QSCALE : 1.0f;

    const int t  = threadIdx.x;
    const int kr = t >> 2, kc = (t & 3) * 16;
    const float* src = W + (size_t)(kt * 64 + kr) * DH + kc;
    float4 a0 = *(const float4*)(src);
    float4 a1 = *(const float4*)(src + 4);
    float4 a2 = *(const float4*)(src + 8);
    float4 a3 = *(const float4*)(src + 12);
    float vv[16] = {a0.x,a0.y,a0.z,a0.w, a1.x,a1.y,a1.z,a1.w,
                    a2.x,a2.y,a2.z,a2.w, a3.x,a3.y,a3.z,a3.w};
    #pragma unroll
    for (int i = 0; i < 16; ++i) tr[kr][kc + i] = f2bf(vv[i] * sc);
    __syncthreads();

    const int cl = t >> 2, jc = (t & 3) * 16;
    const int c  = mmat * 64 + cl;
    ushort_t* dst = wts + kt * 12288 + c * 64;
    #pragma unroll
    for (int jj = 0; jj < 16; ++jj) {
        int j = jc + jj;
        dst[((j >> 3) ^ (cl & 7)) * 8 + (j & 7)] = tr[j][cl];
    }
}

// ---------------------------------------------------------------------------
// Kernel 1: fused QKV projection, bf16 MFMA 32x32x16.
// r7 = r5's verified schedule/occupancy + r6's verified 32x32 layouts:
// 512 blocks x 64 rows; 4 waves = 2 row-groups (rh) x 2 col-groups (ch);
// wave = 32 rows x 96 cols -> 12 ds_read_b128 + 12 MFMA per K-step (LDS
// read amplification HALVED vs 16x16 at the SAME 3 blocks/CU occupancy).
// W staged via 2-slot 48 KB ring, r5 counted-vmcnt: per iter issue
// W(kt+1) 6 DMA + x(kt+1) 8 loads, then vmcnt(14) (drains W(kt)+x(kt),
// keeps the 14 newest in flight), barrier, compute, barrier.
// Fragment layouts (HW-verified r2/r6): A m=lane&31, k=ks*16+hs*8+j;
// B n=lane&31; C row=(r&3)+8*(r>>2)+4*hs, col=lane&31.
// ---------------------------------------------------------------------------
__global__ __launch_bounds__(256) void qkv_proj(
    const float* __restrict__ x, const ushort_t* __restrict__ wts,
    const float* __restrict__ bq, const float* __restrict__ bk,
    const float* __restrict__ bv,
    ushort_t* __restrict__ qimg, ushort_t* __restrict__ kimg,
    ushort_t* __restrict__ vimg)
{
    __shared__ ushort_t bw[2][12288];          // 2 x 24 KB W ring

    const int t  = threadIdx.x;
    const int w  = t >> 6, l = t & 63, lw = l & 31, hs = l >> 5;
    const int rh = w & 1;                      // row-group (which 32 rows)
    const int ch = w >> 1;                     // col-group (which 96 cols)
    const int row0 = blockIdx.x * 64;
    const int row  = row0 + rh * 32 + lw;      // A m-index = lane&31

    f32x16 acc[3];
    #pragma unroll
    for (int i = 0; i < 3; ++i)
        for (int r = 0; r < 16; ++r) acc[i][r] = 0.f;

    const char* wbase = (const char*)wts;
    const int   wlo   = w * 1024 + l * 16;     // lane byte offset in 24 KB slice
    const float* xrow = x + (size_t)row * HID + hs * 8;

    auto STAGEW = [&](int ss, int tile) {
        char* bdst = (char*)&bw[ss][0] + w * 1024;
        const char* bsrc = wbase + (size_t)tile * 24576 + wlo;
        #pragma unroll
        for (int i = 0; i < 6; ++i)
            gld_lds16(bsrc + i * 4096, bdst + i * 4096);
    };

    float4 Xc[4][2], Xn[4][2];                 // lane's 32 x floats: k = ks*16+hs*8+j

    // prologue: W0 (6 DMA) + x0 (8 loads)
    STAGEW(0, 0);
    #pragma unroll
    for (int ks = 0; ks < 4; ++ks) {
        Xc[ks][0] = *(const float4*)(xrow + ks * 16);
        Xc[ks][1] = *(const float4*)(xrow + ks * 16 + 4);
    }

    for (int kt = 0; kt < 16; ++kt) {
        const int buf = kt & 1;
        if (kt < 15) {                         // stage W(kt+1) + x(kt+1): 14 newest
            STAGEW(buf ^ 1, kt + 1);
            const float* xn = xrow + (kt + 1) * 64;
            #pragma unroll
            for (int ks = 0; ks < 4; ++ks) {
                Xn[ks][0] = *(const float4*)(xn + ks * 16);
                Xn[ks][1] = *(const float4*)(xn + ks * 16 + 4);
            }
        }
        // drain W(kt)+x(kt); keep the 14 newest (kt+1's) in flight
        if (kt < 15) asm volatile("s_waitcnt vmcnt(14)" ::: "memory");
        else         asm volatile("s_waitcnt vmcnt(0)"  ::: "memory");
        __builtin_amdgcn_s_barrier();
        asm volatile("" ::: "memory");

        // pack A fragments (k ascending)
        bf16x8 af[4];
        #pragma unroll
        for (int ks = 0; ks < 4; ++ks) {
            u32x4 p;
            p.x = bfpair(Xc[ks][0].x, Xc[ks][0].y);
            p.y = bfpair(Xc[ks][0].z, Xc[ks][0].w);
            p.z = bfpair(Xc[ks][1].x, Xc[ks][1].y);
            p.w = bfpair(Xc[ks][1].z, Xc[ks][1].w);
            af[ks] = *(bf16x8*)&p;
        }
        // 12 MFMAs (32x32x16) over this wave's 3 col-tiles of 32
        const ushort_t* bwS = &bw[buf][0];
        #pragma unroll
        for (int ct = 0; ct < 3; ++ct) {
            const int c32 = ch * 3 + ct;                  // 32-col tile idx 0..5
            const ushort_t* bp = bwS + (c32 * 32 + lw) * 64;
            #pragma unroll
            for (int ks = 0; ks < 4; ++ks) {
                bf16x8 bf = *(const bf16x8*)(bp + (((ks * 2 + hs) ^ (lw & 7)) * 8));
                acc[ct] = __builtin_amdgcn_mfma_f32_32x32x16_bf16(af[ks], bf, acc[ct], 0, 0, 0);
            }
        }
        asm volatile("" ::: "memory");
        __builtin_amdgcn_s_barrier();          // protect bw[buf^1] rewrite next iter
        #pragma unroll
        for (int ks = 0; ks < 4; ++ks) { Xc[ks][0] = Xn[ks][0]; Xc[ks][1] = Xn[ks][1]; }
    }

    // epilogue: +bias, cast, scatter. C: row = (r&3)+8*(r>>2)+4*hs, col = lw.
    // col c = c32*32+lw -> mmat = c32>>1, cc = ((c32&1)<<5)|lw (uniform per ct).
    const int rowbase = row0 + rh * 32;
    #pragma unroll
    for (int ct = 0; ct < 3; ++ct) {
        const int c32  = ch * 3 + ct;
        const int mmat = c32 >> 1;
        const int cc   = ((c32 & 1) << 5) | lw;
        const float* bpv = (mmat == 0) ? bq : (mmat == 1) ? bk : bv;
        const float bias = bpv[cc] * (mmat == 0 ? QSCALE : 1.0f);
        #pragma unroll
        for (int r = 0; r < 16; ++r) {
            const int s = rowbase + (r & 3) + 8 * (r >> 2) + 4 * hs;
            const ushort_t v = f2bf_fast(acc[ct][r] + bias);
            if (mmat == 0)
                qimg[(size_t)s * 64 + cc] = v;
            else if (mmat == 1)
                kimg[(size_t)(s >> 6) * 4096 + (s & 63) * 64 +
                     ((cc >> 3) ^ (s & 7)) * 8 + (cc & 7)] = v;
            else
                vimg[(size_t)(s >> 6) * 4096 + (size_t)cc * 64 +
                     (((s & 63) >> 3) ^ (cc & 7)) * 8 + (s & 7)] = v;
        }
    }
}

// ---------------------------------------------------------------------------
// Kernel 2: causal flash attention, bf16 MFMA 32x32x16, S^T form, 2-way kv
// split-K across blocks (1024 blocks, LPT, 3 blocks/CU oversubscription).
// Unchanged from round 6 (passed): stage-after-barrier + 3-slot ring ->
// ONE barrier per tile; derived waits vmcnt(4|0).
// ---------------------------------------------------------------------------
__global__ __launch_bounds__(256) void attn(
    const ushort_t* __restrict__ qimg, const ushort_t* __restrict__ kimg,
    const ushort_t* __restrict__ vimg,
    float* __restrict__ Opart, float* __restrict__ Lpart)
{
    __shared__ ushort_t kvs[3][8192];   // ring slot: K bytes 0..8191, V 8192..16383
    float* const oscp  = (float*)&kvs[0][0];   // epilogue alias: 4096 floats
    float* const lredp = (float*)&kvs[1][0];   // epilogue alias: 64 floats

    const int t  = threadIdx.x;
    const int w  = t >> 6, l = t & 63, lw = l & 31, hs = l >> 5;
    const int qh = w & 1;               // q-half of the 64-row q-tile
    const int kh = w >> 1;              // kv-half of each 64-row kv-tile
    const int bx   = blockIdx.x;        // 1024 blocks
    const int half = bx & 1;
    const int u    = bx >> 1;
    const int qt   = 63 - (u >> 3);     // sizes descend pairwise -> LPT
    const int b    = u & 7;
    const int q0   = qt * 64;
    const int n    = qt + 1, hn = n >> 1;
    const int t0   = half ? hn : 0;
    const int t1   = half ? n : hn;
    const int qq   = q0 + qh * 32 + lw;        // this lane's q-row (global)

    // Q as B-fragments (n = q = lane&31, k = d = ks*16 + hs*8 + j)
    bf16x8 qf[4];
    {
        const ushort_t* qp = qimg + (size_t)(b * SEQ + qq) * 64 + hs * 8;
        #pragma unroll
        for (int ks = 0; ks < 4; ++ks) qf[ks] = *(const bf16x8*)(qp + ks * 16);
    }

    f32x16 o0, o1;                      // O[q][d]: d = lw (o0) / 32+lw (o1)
    #pragma unroll
    for (int r = 0; r < 16; ++r) { o0[r] = 0.f; o1[r] = 0.f; }
    float lpart = 0.f;

    const char* kbase = (const char*)kimg + (size_t)b * 524288;
    const char* vbase = (const char*)vimg + (size_t)b * 524288;
    const int wo = w * 1024;
    const int lo = l * 16;

    auto STAGE = [&](int ss, int tt) {
        const char* ks = kbase + (size_t)tt * 8192;
        const char* vs = vbase + (size_t)tt * 8192;
        char* lk = (char*)&kvs[ss][0];
        gld_lds16(ks + wo + lo,        lk + wo);
        gld_lds16(ks + wo + lo + 4096, lk + wo + 4096);
        gld_lds16(vs + wo + lo,        lk + wo + 8192);
        gld_lds16(vs + wo + lo + 4096, lk + wo + 12288);
    };

    // prologue: stage up to 2 tiles ahead (Q loads are the oldest in queue)
    if (t0     < t1) STAGE(0, t0);
    if (t0 + 1 < t1) STAGE(1, t0 + 1);

    int cur = 0;                         // ring slot of current tile
    for (int kt = t0; kt < t1; ++kt) {
        // drain tile kt (and Q on the first iter); keep newest 4 in flight
        if (kt + 1 < t1) asm volatile("s_waitcnt vmcnt(4)" ::: "memory");
        else             asm volatile("s_waitcnt vmcnt(0)" ::: "memory");
        __builtin_amdgcn_s_barrier();
        asm volatile("" ::: "memory");
        if (kt + 2 < t1) {               // stage tile kt+2 into freed slot
            const int sd = (cur == 0) ? 2 : cur - 1;    // (cur+2)%3
            STAGE(sd, kt + 2);
        }

        // S^T = K . Q^T : A = K rows (m = kv, this wave's 32-row kv-half)
        const ushort_t* kb   = &kvs[cur][0];
        const int       krow = kh * 32 + lw;           // A m-index = lane&31
        const ushort_t* krb  = kb + krow * 64;
        f32x16 s;
        #pragma unroll
        for (int r = 0; r < 16; ++r) s[r] = 0.f;
        #pragma unroll
        for (int ks = 0; ks < 4; ++ks) {
            bf16x8 kf = *(const bf16x8*)(krb + (((ks * 2 + hs) ^ (krow & 7)) * 8));
            s = __builtin_amdgcn_mfma_f32_32x32x16_bf16(kf, qf[ks], s, 0, 0, 0);
        }

        // exp2 (+ causal mask on the diagonal tile).
        // reg r holds kv-local = kh*32 + (r&3) + 8*(r>>2) + 4*hs, q = qq.
        float p[16];
        if (kt == qt) {
            #pragma unroll
            for (int r = 0; r < 16; ++r) {
                const int kvg = kt * 64 + kh * 32 + (r & 3) + 8 * (r >> 2) + 4 * hs;
                p[r] = (kvg > qq) ? 0.f : __builtin_amdgcn_exp2f(s[r]);
            }
        } else {
            #pragma unroll
            for (int r = 0; r < 16; ++r) p[r] = __builtin_amdgcn_exp2f(s[r]);
        }
        {
            float s0 = (p[0] + p[1])  + (p[2] + p[3]);
            float s1 = (p[4] + p[5])  + (p[6] + p[7]);
            float s2 = (p[8] + p[9])  + (p[10] + p[11]);
            float s3 = (p[12] + p[13]) + (p[14] + p[15]);
            lpart += (s0 + s1) + (s2 + s3);
        }

        // O += P . V : A = P (m = q, in-register via cvt_pk + permlane32_swap),
        //              B = V^T rows (n = d), k = kv-local 16 per mfma.
        const ushort_t* vb = &kvs[cur][4096];
        #pragma unroll
        for (int ks2 = 0; ks2 < 2; ++ks2) {
            uint_t a0 = bfpair(p[ks2*8 + 0], p[ks2*8 + 1]);
            uint_t b0 = bfpair(p[ks2*8 + 4], p[ks2*8 + 5]);
            uint_t a1 = bfpair(p[ks2*8 + 2], p[ks2*8 + 3]);
            uint_t b1 = bfpair(p[ks2*8 + 6], p[ks2*8 + 7]);
            asm("v_permlane32_swap_b32 %0, %1" : "+v"(a0), "+v"(b0));
            asm("v_permlane32_swap_b32 %0, %1" : "+v"(a1), "+v"(b1));
            u32x4 pw = { a0, a1, b0, b1 };
            bf16x8 paf = *(bf16x8*)&pw;
            const int sl8 = kh * 4 + ks2 * 2 + hs;     // (kv-local)>>3 chunk
            {
                const int vr0 = lw;                    // n = d = lw
                bf16x8 vf0 = *(const bf16x8*)(vb + vr0 * 64 + ((sl8 ^ (vr0 & 7)) * 8));
                o0 = __builtin_amdgcn_mfma_f32_32x32x16_bf16(paf, vf0, o0, 0, 0, 0);
                const int vr1 = 32 + lw;               // n = d = 32+lw
                bf16x8 vf1 = *(const bf16x8*)(vb + vr1 * 64 + ((sl8 ^ (vr1 & 7)) * 8));
                o1 = __builtin_amdgcn_mfma_f32_32x32x16_bf16(paf, vf1, o1, 0, 0, 0);
            }
        }
        cur = (cur == 2) ? 0 : cur + 1;
    }
    __syncthreads();                     // all reads of kvs done before aliasing

    // ---- cross-wave combine: kv-half pairs (w, w+2) share q-half qh ----
    if (kh == 1) {                       // donors: dump O and l to scratch
        const int lbase = (qh * 64 + l) * 32;
        #pragma unroll
        for (int i = 0; i < 4; ++i) {
            f32x4 v = { o0[4*i], o0[4*i+1], o0[4*i+2], o0[4*i+3] };
            *(f32x4*)&oscp[lbase + ((i ^ (l & 7)) * 4)] = v;
        }
        #pragma unroll
        for (int i = 0; i < 4; ++i) {
            f32x4 v = { o1[4*i], o1[4*i+1], o1[4*i+2], o1[4*i+3] };
            *(f32x4*)&oscp[lbase + (((i + 4) ^ (l & 7)) * 4)] = v;
        }
        float lsum = lpart + __shfl_xor(lpart, 32);
        if (hs == 0) lredp[qh * 32 + lw] = lsum;
    }
    __syncthreads();
    if (kh == 0) {                       // readers: combine + store partials
        const int lbase = (qh * 64 + l) * 32;
        #pragma unroll
        for (int i = 0; i < 4; ++i) {
            f32x4 v = *(const f32x4*)&oscp[lbase + ((i ^ (l & 7)) * 4)];
            o0[4*i] += v.x; o0[4*i+1] += v.y; o0[4*i+2] += v.z; o0[4*i+3] += v.w;
        }
        #pragma unroll
        for (int i = 0; i < 4; ++i) {
            f32x4 v = *(const f32x4*)&oscp[lbase + (((i + 4) ^ (l & 7)) * 4)];
            o1[4*i] += v.x; o1[4*i+1] += v.y; o1[4*i+2] += v.z; o1[4*i+3] += v.w;
        }
        const float lt = (lpart + __shfl_xor(lpart, 32)) + lredp[qh * 32 + lw];

        const int m = b * 64 + qt;
        float* Op = Opart + ((size_t)half * 512 + m) * 4096;
        #pragma unroll
        for (int r = 0; r < 16; ++r) {
            const int qrow = qh * 32 + (r & 3) + 8 * (r >> 2) + 4 * hs;
            Op[qrow * 64 + lw]      = o0[r];
            Op[qrow * 64 + 32 + lw] = o1[r];
        }
        if (hs == 0)
            Lpart[((size_t)half * 512 + m) * 64 + qh * 32 + lw] = lt;
    }
}

// ---------------------------------------------------------------------------
// Kernel 3: merge split-K halves: out = (Oa + Ob) / (la + lb)
// ---------------------------------------------------------------------------
__global__ __launch_bounds__(256) void merge_o(
    const float* __restrict__ Opart, const float* __restrict__ Lpart,
    float* __restrict__ outg)
{
    const int m = blockIdx.x;           // b*64 + qt
    const int b = m >> 6, qt = m & 63;
    const int t = threadIdx.x;
    const int row = t >> 2, c = (t & 3) * 16;

    const float* A = Opart + (size_t)m * 4096 + row * 64 + c;
    const float* B = Opart + (size_t)(512 + m) * 4096 + row * 64 + c;
    const float la = Lpart[(size_t)m * 64 + row];
    const float lb = Lpart[(size_t)(512 + m) * 64 + row];
    const float inv = 1.0f / (la + lb);
    float* dst = outg + ((size_t)b * SEQ + qt * 64 + row) * 64 + c;
    #pragma unroll
    for (int j = 0; j < 4; ++j) {
        float4 va = *(const float4*)(A + j * 4);
        float4 vb = *(const float4*)(B + j * 4);
        float4 vo = { (va.x + vb.x) * inv, (va.y + vb.y) * inv,
                      (va.z + vb.z) * inv, (va.w + vb.w) * inv };
        *(float4*)(dst + j * 4) = vo;
    }
}

extern "C" void kernel_launch(void* const* d_in, const int* in_sizes, int n_in,
                              void* d_out, int out_size, void* d_ws, size_t ws_size,
                              hipStream_t stream) {
    const float* x  = (const float*)d_in[0];
    const float* Wq = (const float*)d_in[1];
    const float* bq = (const float*)d_in[2];
    const float* Wk = (const float*)d_in[3];
    const float* bk = (const float*)d_in[4];
    const float* Wv = (const float*)d_in[5];
    const float* bv = (const float*)d_in[6];
    float* out = (float*)d_out;

    const size_t per = (size_t)NB * SEQ * DH;   // 2,097,152 bf16 elems = 4 MB
    ushort_t* q   = (ushort_t*)d_ws;
    ushort_t* k   = q + per;
    ushort_t* v   = k + per;
    ushort_t* wts = v + per;                    // 384 KB
    float* Opart  = (float*)((char*)d_ws + (size_t)(16u << 20));  // 16.8 MB
    float* Lpart  = (float*)((char*)d_ws + (size_t)(40u << 20));  // 256 KB

    prep_w  <<<dim3(48),   256, 0, stream>>>(Wq, Wk, Wv, wts);
    qkv_proj<<<dim3(512),  256, 0, stream>>>(x, wts, bq, bk, bv, q, k, v);
    attn    <<<dim3(1024), 256, 0, stream>>>(q, k, v, Opart, Lpart);
    merge_o <<<dim3(512),  256, 0, stream>>>(Opart, Lpart, out);
}

// Round 8
// 249.049 us; speedup vs baseline: 1.0512x; 1.0512x over previous
//
#include <hip/hip_runtime.h>
#include <hip/hip_bf16.h>
#include <math.h>

#define SEQ 4096
#define HID 1024
#define DH  64
#define NB  8
#define QSCALE 0.18033688011112042f   // 0.125 * log2(e): folds softmax scale + exp->exp2

typedef unsigned short ushort_t;
typedef unsigned int   uint_t;
typedef __attribute__((ext_vector_type(8)))  short  bf16x8;
typedef __attribute__((ext_vector_type(4)))  float  f32x4;
typedef __attribute__((ext_vector_type(16))) float  f32x16;
typedef __attribute__((ext_vector_type(4)))  uint_t u32x4;
typedef __attribute__((ext_vector_type(2)))  uint_t u32x2;

static __device__ __forceinline__ ushort_t f2bf(float f) {
    __hip_bfloat16 h = __float2bfloat16(f);   // RNE
    return *reinterpret_cast<ushort_t*>(&h);
}
// fast round-to-nearest bf16 (no NaN path; inputs finite)
static __device__ __forceinline__ ushort_t f2bf_fast(float f) {
    uint_t u = __float_as_uint(f);
    return (ushort_t)((u + 0x8000u) >> 16);
}
static __device__ __forceinline__ uint_t bfpair(float lo, float hi) {
    return (uint_t)f2bf_fast(lo) | ((uint_t)f2bf_fast(hi) << 16);
}

// async global->LDS DMA, 16 B per lane; lds dest = wave-uniform base + lane*16
static __device__ __forceinline__ void gld_lds16(const void* g, void* s) {
    __builtin_amdgcn_global_load_lds(
        (const __attribute__((address_space(1))) void*)g,
        (__attribute__((address_space(3))) void*)s, 16, 0, 0);
}

// ---------------------------------------------------------------------------
// Kernel 0: build wts = [Wq*QSCALE | Wk | Wv] transposed to [col][k], bf16,
// pre-swizzled per 64-k tile so proj can stage it as a flat DMA copy.
// ---------------------------------------------------------------------------
__global__ __launch_bounds__(256) void prep_w(
    const float* __restrict__ Wq, const float* __restrict__ Wk,
    const float* __restrict__ Wv, ushort_t* __restrict__ wts)
{
    __shared__ ushort_t tr[64][72];   // [k][c] bf16
    const int bx   = blockIdx.x;      // 48 = 3 mats x 16 k-tiles
    const int mmat = bx >> 4;
    const int kt   = bx & 15;
    const float* W  = (mmat == 0) ? Wq : (mmat == 1) ? Wk : Wv;
    const float  sc = (mmat == 0) ? QSCALE : 1.0f;

    const int t  = threadIdx.x;
    const int kr = t >> 2, kc = (t & 3) * 16;
    const float* src = W + (size_t)(kt * 64 + kr) * DH + kc;
    float4 a0 = *(const float4*)(src);
    float4 a1 = *(const float4*)(src + 4);
    float4 a2 = *(const float4*)(src + 8);
    float4 a3 = *(const float4*)(src + 12);
    float vv[16] = {a0.x,a0.y,a0.z,a0.w, a1.x,a1.y,a1.z,a1.w,
                    a2.x,a2.y,a2.z,a2.w, a3.x,a3.y,a3.z,a3.w};
    #pragma unroll
    for (int i = 0; i < 16; ++i) tr[kr][kc + i] = f2bf(vv[i] * sc);
    __syncthreads();

    const int cl = t >> 2, jc = (t & 3) * 16;
    const int c  = mmat * 64 + cl;
    ushort_t* dst = wts + kt * 12288 + c * 64;
    #pragma unroll
    for (int jj = 0; jj < 16; ++jj) {
        int j = jc + jj;
        dst[((j >> 3) ^ (cl & 7)) * 8 + (j & 7)] = tr[j][cl];
    }
}

// ---------------------------------------------------------------------------
// Kernel 1: fused QKV projection, bf16 MFMA 16x16x32 — EXACT round-5 version
// (best verified). Counted-vmcnt pipeline: stage W(kt+1) + x(kt+1) FIRST,
// then vmcnt(14) (drains W(kt)+x(kt), keeps the 14 newest in flight),
// raw s_barrier, compute, barrier. No setprio (4-wave lockstep = m190 null).
// ---------------------------------------------------------------------------
__global__ __launch_bounds__(256) void qkv_proj(
    const float* __restrict__ x, const ushort_t* __restrict__ wts,
    const float* __restrict__ bq, const float* __restrict__ bk,
    const float* __restrict__ bv,
    ushort_t* __restrict__ qimg, ushort_t* __restrict__ kimg,
    ushort_t* __restrict__ vimg)
{
    __shared__ ushort_t bw[2][12288];

    const int t  = threadIdx.x;
    const int w  = t >> 6, l = t & 63, lr = l & 15, g = l >> 4;
    const int row0 = blockIdx.x * 64;
    const int row  = row0 + w * 16 + lr;       // this lane's x-row (A m-index = lr)
    const int ch0 = (g ^ (lr & 7)) * 8;
    const int ch1 = ((g + 4) ^ (lr & 7)) * 8;

    f32x4 acc[12];
    #pragma unroll
    for (int i = 0; i < 12; ++i) acc[i] = (f32x4){0.f,0.f,0.f,0.f};

    const char* wbase = (const char*)wts;
    const int   wlo   = w * 1024 + l * 16;     // lane byte offset in 24 KB slice
    const float* xrow = x + (size_t)row * HID + g * 8;

    float4 Xa0, Xa1, Xb0, Xb1;                 // current tile: af0 <- Xa*, af1 <- Xb*
    {   // prologue: X tile 0 regs + DMA W tile 0 -> bw[0]
        Xa0 = *(const float4*)(xrow);
        Xa1 = *(const float4*)(xrow + 4);
        Xb0 = *(const float4*)(xrow + 32);
        Xb1 = *(const float4*)(xrow + 36);
        char* bdst = (char*)&bw[0][0] + w * 1024;
        #pragma unroll
        for (int i = 0; i < 6; ++i)
            gld_lds16(wbase + wlo + i * 4096, bdst + i * 4096);
    }

    for (int kt = 0; kt < 16; ++kt) {
        const int buf = kt & 1;
        float4 Na0, Na1, Nb0, Nb1;
        if (kt < 15) {                         // stage W tile kt+1 (6 DMA ops)
            char* bdst = (char*)&bw[buf ^ 1][0] + w * 1024;
            const char* bsrc = wbase + (size_t)(kt + 1) * 24576 + wlo;
            #pragma unroll
            for (int i = 0; i < 6; ++i)
                gld_lds16(bsrc + i * 4096, bdst + i * 4096);
            const float* xn = xrow + (kt + 1) * 64;   // x prefetch (4 loads)
            Na0 = *(const float4*)(xn);
            Na1 = *(const float4*)(xn + 4);
            Nb0 = *(const float4*)(xn + 32);
            Nb1 = *(const float4*)(xn + 36);
        }
        // counted wait: drain THIS tile's W DMAs (oldest), keep next tile's
        // 6 DMAs + 4 x-loads (the 10 newest) in flight.
        if (kt < 15) asm volatile("s_waitcnt vmcnt(10)" ::: "memory");
        else         asm volatile("s_waitcnt vmcnt(0)"  ::: "memory");
        __builtin_amdgcn_s_barrier();
        asm volatile("" ::: "memory");

        // convert current X regs -> A fragments (k = g*8 + j)
        bf16x8 af0, af1;
        {
            u32x4 p;
            p.x = bfpair(Xa0.x, Xa0.y); p.y = bfpair(Xa0.z, Xa0.w);
            p.z = bfpair(Xa1.x, Xa1.y); p.w = bfpair(Xa1.z, Xa1.w);
            af0 = *(bf16x8*)&p;
            u32x4 q;
            q.x = bfpair(Xb0.x, Xb0.y); q.y = bfpair(Xb0.z, Xb0.w);
            q.z = bfpair(Xb1.x, Xb1.y); q.w = bfpair(Xb1.z, Xb1.w);
            af1 = *(bf16x8*)&q;
        }
        // 24 MFMAs over all 12 col-tiles
        #pragma unroll
        for (int ct = 0; ct < 12; ++ct) {
            const int c = ct * 16 + lr;
            bf16x8 b0 = *(bf16x8*)&bw[buf][c * 64 + ch0];
            bf16x8 b1 = *(bf16x8*)&bw[buf][c * 64 + ch1];
            acc[ct] = __builtin_amdgcn_mfma_f32_16x16x32_bf16(af0, b0, acc[ct], 0, 0, 0);
            acc[ct] = __builtin_amdgcn_mfma_f32_16x16x32_bf16(af1, b1, acc[ct], 0, 0, 0);
        }
        asm volatile("" ::: "memory");
        __builtin_amdgcn_s_barrier();          // protect bw[buf^1] rewrite next iter
        Xa0 = Na0; Xa1 = Na1; Xb0 = Nb0; Xb1 = Nb1;
    }

    // epilogue: +bias, cast, scatter to layout images.
    // C layout: lane (lr,g) holds D[row = w*16 + g*4 + r][col = ct*16 + lr]
    #pragma unroll
    for (int ct = 0; ct < 12; ++ct) {
        const int c    = ct * 16 + lr;
        const int mmat = c >> 6;
        const int cc   = c & 63;
        const float* bp = (mmat == 0) ? bq : (mmat == 1) ? bk : bv;
        const float bias = bp[cc] * (mmat == 0 ? QSCALE : 1.0f);
        #pragma unroll
        for (int r = 0; r < 4; ++r) {
            const int s = row0 + w * 16 + g * 4 + r;
            const ushort_t v = f2bf_fast(acc[ct][r] + bias);
            if (mmat == 0)
                qimg[(size_t)s * 64 + cc] = v;
            else if (mmat == 1)
                kimg[(size_t)(s >> 6) * 4096 + (s & 63) * 64 +
                     ((cc >> 3) ^ (s & 7)) * 8 + (cc & 7)] = v;
            else
                vimg[(size_t)(s >> 6) * 4096 + (size_t)cc * 64 +
                     (((s & 63) >> 3) ^ (cc & 7)) * 8 + (s & 7)] = v;
        }
    }
}

// ---------------------------------------------------------------------------
// Kernel 2: causal flash attention, bf16 MFMA 32x32x16, S^T form, 2-way kv
// split-K (1024 blocks, LPT, 3 blocks/CU). EXACT round-5 schedule (best
// verified): 3-slot ring, STAGE(kt+2) issued BEFORE the counted wait
// (stage-before-wait keeps depth-8 in flight THROUGH the wait — the r6/r7
// single-barrier variant that waited first lost ~9 µs), vmcnt(8/4/0),
// barrier, compute, barrier.
// NEW (isolated): s_setprio(1) around the two MFMA clusters, prio 0 through
// the exp2/pack VALU phase — m191 regime (independent blocks, no lockstep).
// ---------------------------------------------------------------------------
__global__ __launch_bounds__(256) void attn(
    const ushort_t* __restrict__ qimg, const ushort_t* __restrict__ kimg,
    const ushort_t* __restrict__ vimg,
    float* __restrict__ Opart, float* __restrict__ Lpart)
{
    __shared__ ushort_t kvs[3][8192];   // ring slot: K bytes 0..8191, V 8192..16383
    float* const oscp  = (float*)&kvs[0][0];   // epilogue alias: 4096 floats
    float* const lredp = (float*)&kvs[1][0];   // epilogue alias: 64 floats

    const int t  = threadIdx.x;
    const int w  = t >> 6, l = t & 63, lw = l & 31, hs = l >> 5;
    const int qh = w & 1;               // q-half of the 64-row q-tile
    const int kh = w >> 1;              // kv-half of each 64-row kv-tile
    const int bx   = blockIdx.x;        // 1024 blocks
    const int half = bx & 1;
    const int u    = bx >> 1;
    const int qt   = 63 - (u >> 3);     // sizes descend pairwise -> LPT
    const int b    = u & 7;
    const int q0   = qt * 64;
    const int n    = qt + 1, hn = n >> 1;
    const int t0   = half ? hn : 0;
    const int t1   = half ? n : hn;
    const int qq   = q0 + qh * 32 + lw;        // this lane's q-row (global)

    // Q as B-fragments (n = q = lane&31, k = d = ks*16 + hs*8 + j)
    bf16x8 qf[4];
    {
        const ushort_t* qp = qimg + (size_t)(b * SEQ + qq) * 64 + hs * 8;
        #pragma unroll
        for (int ks = 0; ks < 4; ++ks) qf[ks] = *(const bf16x8*)(qp + ks * 16);
    }

    f32x16 o0, o1;                      // O[q][d]: d = lw (o0) / 32+lw (o1)
    #pragma unroll
    for (int r = 0; r < 16; ++r) { o0[r] = 0.f; o1[r] = 0.f; }
    float lpart = 0.f;

    const char* kbase = (const char*)kimg + (size_t)b * 524288;
    const char* vbase = (const char*)vimg + (size_t)b * 524288;
    const int wo = w * 1024;
    const int lo = l * 16;

    auto STAGE = [&](int ss, int tt) {
        const char* ks = kbase + (size_t)tt * 8192;
        const char* vs = vbase + (size_t)tt * 8192;
        char* lk = (char*)&kvs[ss][0];
        gld_lds16(ks + wo + lo,        lk + wo);
        gld_lds16(ks + wo + lo + 4096, lk + wo + 4096);
        gld_lds16(vs + wo + lo,        lk + wo + 8192);
        gld_lds16(vs + wo + lo + 4096, lk + wo + 12288);
    };

    // prologue: stage up to 2 tiles ahead
    if (t0     < t1) STAGE(0, t0);
    if (t0 + 1 < t1) STAGE(1, t0 + 1);

    int cur = 0;                         // ring slot of current tile
    for (int kt = t0; kt < t1; ++kt) {
        const int sd = (cur == 0) ? 2 : cur - 1;   // (i+2)%3: slot freed at i-1
        if (kt + 2 < t1) STAGE(sd, kt + 2);
        // counted wait AFTER staging: drain THIS tile's 4 DMAs (oldest);
        // keep the newest 8 (tiles kt+1, kt+2) in flight through the wait.
        if      (kt + 2 < t1) asm volatile("s_waitcnt vmcnt(8)" ::: "memory");
        else if (kt + 1 < t1) asm volatile("s_waitcnt vmcnt(4)" ::: "memory");
        else                  asm volatile("s_waitcnt vmcnt(0)" ::: "memory");
        __builtin_amdgcn_s_barrier();
        asm volatile("" ::: "memory");

        // S^T = K . Q^T : A = K rows (m = kv, this wave's 32-row kv-half)
        const ushort_t* kb   = &kvs[cur][0];
        const int       krow = kh * 32 + lw;           // A m-index = lane&31
        const ushort_t* krb  = kb + krow * 64;
        f32x16 s;
        #pragma unroll
        for (int r = 0; r < 16; ++r) s[r] = 0.f;
        __builtin_amdgcn_s_setprio(1);
        #pragma unroll
        for (int ks = 0; ks < 4; ++ks) {
            bf16x8 kf = *(const bf16x8*)(krb + (((ks * 2 + hs) ^ (krow & 7)) * 8));
            s = __builtin_amdgcn_mfma_f32_32x32x16_bf16(kf, qf[ks], s, 0, 0, 0);
        }
        __builtin_amdgcn_s_setprio(0);

        // exp2 (+ causal mask on the diagonal tile) — VALU phase at prio 0.
        // reg r holds kv-local = kh*32 + (r&3) + 8*(r>>2) + 4*hs, q = qq.
        float p[16];
        if (kt == qt) {
            #pragma unroll
            for (int r = 0; r < 16; ++r) {
                const int kvg = kt * 64 + kh * 32 + (r & 3) + 8 * (r >> 2) + 4 * hs;
                p[r] = (kvg > qq) ? 0.f : __builtin_amdgcn_exp2f(s[r]);
            }
        } else {
            #pragma unroll
            for (int r = 0; r < 16; ++r) p[r] = __builtin_amdgcn_exp2f(s[r]);
        }
        {
            float s0 = (p[0] + p[1])  + (p[2] + p[3]);
            float s1 = (p[4] + p[5])  + (p[6] + p[7]);
            float s2 = (p[8] + p[9])  + (p[10] + p[11]);
            float s3 = (p[12] + p[13]) + (p[14] + p[15]);
            lpart += (s0 + s1) + (s2 + s3);
        }

        // O += P . V : A = P (m = q, in-register via cvt_pk + permlane32_swap),
        //              B = V^T rows (n = d), k = kv-local 16 per mfma.
        const ushort_t* vb = &kvs[cur][4096];
        #pragma unroll
        for (int ks2 = 0; ks2 < 2; ++ks2) {
            uint_t a0 = bfpair(p[ks2*8 + 0], p[ks2*8 + 1]);
            uint_t b0 = bfpair(p[ks2*8 + 4], p[ks2*8 + 5]);
            uint_t a1 = bfpair(p[ks2*8 + 2], p[ks2*8 + 3]);
            uint_t b1 = bfpair(p[ks2*8 + 6], p[ks2*8 + 7]);
            asm("v_permlane32_swap_b32 %0, %1" : "+v"(a0), "+v"(b0));
            asm("v_permlane32_swap_b32 %0, %1" : "+v"(a1), "+v"(b1));
            u32x4 pw = { a0, a1, b0, b1 };
            bf16x8 paf = *(bf16x8*)&pw;
            const int sl8 = kh * 4 + ks2 * 2 + hs;     // (kv-local)>>3 chunk
            __builtin_amdgcn_s_setprio(1);
            {
                const int vr0 = lw;                    // n = d = lw
                bf16x8 vf0 = *(const bf16x8*)(vb + vr0 * 64 + ((sl8 ^ (vr0 & 7)) * 8));
                o0 = __builtin_amdgcn_mfma_f32_32x32x16_bf16(paf, vf0, o0, 0, 0, 0);
                const int vr1 = 32 + lw;               // n = d = 32+lw
                bf16x8 vf1 = *(const bf16x8*)(vb + vr1 * 64 + ((sl8 ^ (vr1 & 7)) * 8));
                o1 = __builtin_amdgcn_mfma_f32_32x32x16_bf16(paf, vf1, o1, 0, 0, 0);
            }
            __builtin_amdgcn_s_setprio(0);
        }
        asm volatile("" ::: "memory");
        __builtin_amdgcn_s_barrier();     // slot sd rewrite next iter is safe
        cur = (cur == 2) ? 0 : cur + 1;
    }

    // ---- cross-wave combine: kv-half pairs (w, w+2) share q-half qh ----
    // (osc/lred alias the ring; all waves passed the final barrier, no DMA
    //  outstanding -> safe to reuse.)
    if (kh == 1) {                       // donors: dump O and l to scratch
        const int lbase = (qh * 64 + l) * 32;
        #pragma unroll
        for (int i = 0; i < 4; ++i) {
            f32x4 v = { o0[4*i], o0[4*i+1], o0[4*i+2], o0[4*i+3] };
            *(f32x4*)&oscp[lbase + ((i ^ (l & 7)) * 4)] = v;
        }
        #pragma unroll
        for (int i = 0; i < 4; ++i) {
            f32x4 v = { o1[4*i], o1[4*i+1], o1[4*i+2], o1[4*i+3] };
            *(f32x4*)&oscp[lbase + (((i + 4) ^ (l & 7)) * 4)] = v;
        }
        float lsum = lpart + __shfl_xor(lpart, 32);
        if (hs == 0) lredp[qh * 32 + lw] = lsum;
    }
    __syncthreads();
    if (kh == 0) {                       // readers: combine + store partials
        const int lbase = (qh * 64 + l) * 32;
        #pragma unroll
        for (int i = 0; i < 4; ++i) {
            f32x4 v = *(const f32x4*)&oscp[lbase + ((i ^ (l & 7)) * 4)];
            o0[4*i] += v.x; o0[4*i+1] += v.y; o0[4*i+2] += v.z; o0[4*i+3] += v.w;
        }
        #pragma unroll
        for (int i = 0; i < 4; ++i) {
            f32x4 v = *(const f32x4*)&oscp[lbase + (((i + 4) ^ (l & 7)) * 4)];
            o1[4*i] += v.x; o1[4*i+1] += v.y; o1[4*i+2] += v.z; o1[4*i+3] += v.w;
        }
        const float lt = (lpart + __shfl_xor(lpart, 32)) + lredp[qh * 32 + lw];

        const int m = b * 64 + qt;
        float* Op = Opart + ((size_t)half * 512 + m) * 4096;
        #pragma unroll
        for (int r = 0; r < 16; ++r) {
            const int qrow = qh * 32 + (r & 3) + 8 * (r >> 2) + 4 * hs;
            Op[qrow * 64 + lw]      = o0[r];
            Op[qrow * 64 + 32 + lw] = o1[r];
        }
        if (hs == 0)
            Lpart[((size_t)half * 512 + m) * 64 + qh * 32 + lw] = lt;
    }
}

// ---------------------------------------------------------------------------
// Kernel 3: merge split-K halves: out = (Oa + Ob) / (la + lb)
// ---------------------------------------------------------------------------
__global__ __launch_bounds__(256) void merge_o(
    const float* __restrict__ Opart, const float* __restrict__ Lpart,
    float* __restrict__ outg)
{
    const int m = blockIdx.x;           // b*64 + qt
    const int b = m >> 6, qt = m & 63;
    const int t = threadIdx.x;
    const int row = t >> 2, c = (t & 3) * 16;

    const float* A = Opart + (size_t)m * 4096 + row * 64 + c;
    const float* B = Opart + (size_t)(512 + m) * 4096 + row * 64 + c;
    const float la = Lpart[(size_t)m * 64 + row];
    const float lb = Lpart[(size_t)(512 + m) * 64 + row];
    const float inv = 1.0f / (la + lb);
    float* dst = outg + ((size_t)b * SEQ + qt * 64 + row) * 64 + c;
    #pragma unroll
    for (int j = 0; j < 4; ++j) {
        float4 va = *(const float4*)(A + j * 4);
        float4 vb = *(const float4*)(B + j * 4);
        float4 vo = { (va.x + vb.x) * inv, (va.y + vb.y) * inv,
                      (va.z + vb.z) * inv, (va.w + vb.w) * inv };
        *(float4*)(dst + j * 4) = vo;
    }
}

extern "C" void kernel_launch(void* const* d_in, const int* in_sizes, int n_in,
                              void* d_out, int out_size, void* d_ws, size_t ws_size,
                              hipStream_t stream) {
    const float* x  = (const float*)d_in[0];
    const float* Wq = (const float*)d_in[1];
    const float* bq = (const float*)d_in[2];
    const float* Wk = (const float*)d_in[3];
    const float* bk = (const float*)d_in[4];
    const float* Wv = (const float*)d_in[5];
    const float* bv = (const float*)d_in[6];
    float* out = (float*)d_out;

    const size_t per = (size_t)NB * SEQ * DH;   // 2,097,152 bf16 elems = 4 MB
    ushort_t* q   = (ushort_t*)d_ws;
    ushort_t* k   = q + per;
    ushort_t* v   = k + per;
    ushort_t* wts = v + per;                    // 384 KB
    float* Opart  = (float*)((char*)d_ws + (size_t)(16u << 20));  // 16.8 MB
    float* Lpart  = (float*)((char*)d_ws + (size_t)(40u << 20));  // 256 KB

    prep_w  <<<dim3(48),   256, 0, stream>>>(Wq, Wk, Wv, wts);
    qkv_proj<<<dim3(512),  256, 0, stream>>>(x, wts, bq, bk, bv, q, k, v);
    attn    <<<dim3(1024), 256, 0, stream>>>(q, k, v, Opart, Lpart);
    merge_o <<<dim3(512),  256, 0, stream>>>(Opart, Lpart, out);
}